// Round 2
// baseline (542.441 us; speedup 1.0000x reference)
//
#include <hip/hip_runtime.h>

#define B_TOT 32768
#define NF    64
#define NB    33
#define NSEG  32      // NB-1
#define E     64
#define ROWS  32      // b-rows per block
#define NBLK  (B_TOT / ROWS)   // 1024 = 4 blocks/CU, all resident
#define BPAD  35      // bounds row pad: stride 35 -> 2-way LDS aliasing (free)

// ---- kernel 1: P[f][j][e] = bias[f][e] + sum_{i<j} W[f][i][e], j in [0,32) ----
__global__ __launch_bounds__(64) void prefix_kernel(
    const float* __restrict__ W, const float* __restrict__ bias,
    float* __restrict__ P)
{
    const int f = blockIdx.x;
    const int e = threadIdx.x;
    const float* Wf = W + f * (NSEG * E) + e;
    float*       Pf = P + f * (NSEG * E) + e;
    float acc = bias[f * E + e];
    Pf[0] = acc;
    #pragma unroll
    for (int i = 0; i < NSEG - 1; ++i) {
        acc += Wf[i * E];
        Pf[(i + 1) * E] = acc;
    }
}

// ---- kernel 2: stream-writer ----
__global__ __launch_bounds__(256, 4) void pwl_kernel(
    const float* __restrict__ X,       // [B, NF]
    const float* __restrict__ bounds,  // [NF, NB]
    const float* __restrict__ W,       // [NF, NSEG, E]
    const float* __restrict__ P,       // [NF, NSEG, E] (ws)
    float* __restrict__ out)           // [B, NF*E]
{
    __shared__ __align__(16) float  sX[ROWS][NF];    // 8 KB
    __shared__ float                sB[NF][BPAD];    // 8.75 KB
    __shared__ __align__(8)  float2 sJF[ROWS][NF];   // 16 KB
    const int tid = threadIdx.x;
    const int b0  = blockIdx.x * ROWS;

    // stage X slice: 32 rows x 64 f = 2048 floats = 512 float4, fully coalesced
    {
        const float4* Xg  = reinterpret_cast<const float4*>(X + b0 * NF);
        float4*       sX4 = reinterpret_cast<float4*>(&sX[0][0]);
        sX4[tid]       = Xg[tid];
        sX4[tid + 256] = Xg[tid + 256];
    }
    // stage all bounds (64*33 floats)
    for (int i = tid; i < NF * NB; i += 256) {
        const int f = i / NB, k = i - f * NB;
        sB[f][k] = bounds[i];
    }
    __syncthreads();

    // ---- phase A: (j, frac) per (row, f) ----
    {
        const int f  = tid & 63;
        const int rg = tid >> 6;          // 0..3 -> 8 rows each
        float bnd[NB];
        #pragma unroll
        for (int i = 0; i < NB; ++i) bnd[i] = sB[f][i];
        #pragma unroll
        for (int rr = 0; rr < ROWS / 4; ++rr) {
            const int r = rg * (ROWS / 4) + rr;
            const float x = sX[r][f];
            int c = 0;
            #pragma unroll
            for (int i = 0; i < NB; ++i) c += (bnd[i] <= x) ? 1 : 0;
            int j = c - 1;
            j = (j < 0) ? 0 : ((j > NSEG - 1) ? NSEG - 1 : j);
            const float lo = sB[f][j];        // dynamic j: read LDS, not reg array
            const float hi = sB[f][j + 1];
            float fr = (x - lo) / (hi - lo);
            fr = fminf(fmaxf(fr, 0.0f), 1.0f);
            sJF[r][f] = make_float2(fr, __int_as_float(j));
        }
    }
    __syncthreads();

    // ---- phase B: each wave streams 8 full output rows sequentially ----
    const int wave = tid >> 6;
    const int lane = tid & 63;
    const int q    = lane & 15;    // float4 within a 256-B f-chunk
    const int fo   = lane >> 4;    // which of 4 consecutive f's
    const float4* P4   = reinterpret_cast<const float4*>(P);
    const float4* W4   = reinterpret_cast<const float4*>(W);
    float4*       out4 = reinterpret_cast<float4*>(out);

    #pragma unroll
    for (int rr = 0; rr < ROWS / 4; ++rr) {
        const int r = wave * (ROWS / 4) + rr;
        const long rowbase = (long)(b0 + r) * (NF * E / 4);
        #pragma unroll 4
        for (int fb = 0; fb < 16; ++fb) {
            const int f = fb * 4 + fo;
            const float2 jf = sJF[r][f];
            const float fr  = jf.x;
            const int   j   = __float_as_int(jf.y);
            const int   off = (f * NSEG + j) * 16 + q;
            const float4 p = P4[off];
            const float4 w = W4[off];
            float4 res;
            res.x = fmaxf(fmaf(fr, w.x, p.x), 0.0f);
            res.y = fmaxf(fmaf(fr, w.y, p.y), 0.0f);
            res.z = fmaxf(fmaf(fr, w.z, p.z), 0.0f);
            res.w = fmaxf(fmaf(fr, w.w, p.w), 0.0f);
            // 64 lanes x 16 B = 1 KB contiguous; fb walks the row sequentially
            out4[rowbase + fb * 64 + lane] = res;
        }
    }
}

extern "C" void kernel_launch(void* const* d_in, const int* in_sizes, int n_in,
                              void* d_out, int out_size, void* d_ws, size_t ws_size,
                              hipStream_t stream) {
    const float* X      = (const float*)d_in[0];
    const float* bounds = (const float*)d_in[1];
    const float* W      = (const float*)d_in[2];
    const float* bias   = (const float*)d_in[3];
    float* P   = (float*)d_ws;            // 64*32*64*4 = 524288 B scratch
    float* out = (float*)d_out;

    prefix_kernel<<<dim3(NF), dim3(E), 0, stream>>>(W, bias, P);
    pwl_kernel<<<dim3(NBLK), dim3(256), 0, stream>>>(X, bounds, W, P, out);
}